// Round 14
// baseline (1755.048 us; speedup 1.0000x reference)
//
#include <hip/hip_runtime.h>

#define NN 5000
#define EE 80000
#define BB 16
#define TT 64
// HG=64, HT=128

constexpr int ECAP = 1216;                // staged edges per block

typedef float  f32x2 __attribute__((ext_vector_type(2)));
typedef float  f32x4 __attribute__((ext_vector_type(4)));
typedef short  short8 __attribute__((ext_vector_type(8)));

__device__ inline unsigned short f2bf(float f) {           // RNE fp32->bf16 (setup kernels)
  unsigned int u = __builtin_bit_cast(unsigned int, f);
  u = (u + 0x7fffu + ((u >> 16) & 1u)) >> 16;
  return (unsigned short)u;
}
__device__ inline float bf2f(unsigned short h) {
  unsigned int u = ((unsigned int)h) << 16;
  return __builtin_bit_cast(float, u);
}
// v_cvt_pk_bf16_f32: dst = [bf16(hi) : bf16(lo)]  (lo in bits 0..15)
__device__ inline unsigned int cvtpk(float lo, float hi) {
  unsigned int r;
  asm("v_cvt_pk_bf16_f32 %0, %1, %2" : "=v"(r) : "v"(lo), "v"(hi));
  return r;
}
// float4-stride pad: idx delta per lane ≈ 17 ≡ 1 (mod 8) -> lanes walk all 8 bank-quads
__device__ inline int eb4idx(int t) { return t + (t >> 4); }

// ---------------- CSR build (degree-sorted node order) ----------------
__global__ void k_deg(const int* __restrict__ dst, int* __restrict__ deg) {
  int e = blockIdx.x * 256 + threadIdx.x;
  if (e < EE) atomicAdd(&deg[dst[e]], 1);
}

// counting sort of nodes by degree -> perm (slot->node), rank (node->slot)
__global__ __launch_bounds__(1024) void k_sort(const int* __restrict__ deg,
                                               int* __restrict__ perm,
                                               int* __restrict__ rank) {
  __shared__ int hist[256];
  int t = threadIdx.x;
  if (t < 256) hist[t] = 0;
  __syncthreads();
  for (int n = t; n < NN; n += 1024) atomicAdd(&hist[min(deg[n], 255)], 1);
  __syncthreads();
  if (t == 0) { int run = 0; for (int d = 0; d < 256; ++d) { int c = hist[d]; hist[d] = run; run += c; } }
  __syncthreads();
  for (int n = t; n < NN; n += 1024) {
    int d = min(deg[n], 255);
    int p = atomicAdd(&hist[d], 1);
    perm[p] = n;
    rank[n] = p;
  }
}

__global__ __launch_bounds__(1024) void k_scan(const int* __restrict__ deg,
                                               const int* __restrict__ perm,
                                               int* __restrict__ rowptrP,
                                               float* __restrict__ invdegP) {
  __shared__ int part[1024];
  int t = threadIdx.x;
  const int CH = 5;                      // 1024*5 >= 5000
  int base = t * CH;
  int cnt[CH];
  int s = 0;
  for (int i = 0; i < CH; ++i) {
    int idx = base + i;
    int d = (idx < NN) ? deg[perm[idx]] : 0;
    cnt[i] = d; s += d;
  }
  part[t] = s;
  __syncthreads();
  for (int off = 1; off < 1024; off <<= 1) {
    int v = (t >= off) ? part[t - off] : 0;
    __syncthreads();
    part[t] += v;
    __syncthreads();
  }
  int run = part[t] - s;                 // exclusive prefix
  for (int i = 0; i < CH; ++i) {
    int idx = base + i;
    if (idx < NN) {
      rowptrP[idx] = run;
      invdegP[idx] = 1.0f / fmaxf((float)cnt[i], 1.0f);
      run += cnt[i];
    }
  }
  if (t == 0) rowptrP[NN] = EE;
}

__global__ void k_fill(const int* __restrict__ src, const int* __restrict__ dst,
                       const int* __restrict__ rowptrP, const int* __restrict__ rank,
                       int* __restrict__ fill, int* __restrict__ col) {
  int e = blockIdx.x * 256 + threadIdx.x;
  if (e < EE) {
    int r = rank[dst[e]];
    int p = atomicAdd(&fill[r], 1);
    col[rowptrP[r] + p] = src[e];
  }
}

// ------------- per-(b,t) scalar aggregation: alpha = invdeg * sum x[src] -------------
__global__ __launch_bounds__(256) void k_axp(const float* __restrict__ xseq,
                                             const int* __restrict__ rowptrP,
                                             const int* __restrict__ colg,
                                             const float* __restrict__ invdegP,
                                             const int* __restrict__ perm,
                                             float2* __restrict__ axp) {
  int q = blockIdx.x;                    // q = b*TT + t
  __shared__ float xl[NN];
  const float* xs = xseq + (size_t)q * NN;
  for (int i = threadIdx.x; i < NN; i += 256) xl[i] = xs[i];
  __syncthreads();
  for (int ii = threadIdx.x; ii < NN; ii += 256) {   // permuted slots: sorted -> uniform trips
    int r0 = rowptrP[ii], r1 = rowptrP[ii + 1];
    float s = 0.f;
    for (int i = r0; i < r1; ++i) s += xl[colg[i]];
    int pn = perm[ii];
    axp[(size_t)q * NN + pn] = make_float2(s * invdegP[ii], xl[pn]);
  }
}

// ------------- pre-split W2 stack into bf16 hi/lo MFMA fragments -------------
__global__ void k_wsplit(const float* __restrict__ Wl2, const float* __restrict__ Wr2,
                         unsigned short* __restrict__ Bfh, unsigned short* __restrict__ Bfl) {
  int t = blockIdx.x * 256 + threadIdx.x;
  if (t >= 16 * 64) return;
  int frag = t >> 6, lane = t & 63;
  int ks = frag >> 2, tn = frag & 3;
  int nlo = lane & 15, lg = lane >> 4;
  #pragma unroll
  for (int i = 0; i < 8; ++i) {
    int k = ks * 32 + lg * 8 + i;
    int n = tn * 16 + nlo;
    float v = (k < 64) ? Wl2[k * 64 + n] : Wr2[(k - 64) * 64 + n];
    unsigned short h = f2bf(v);
    unsigned short l = f2bf(v - bf2f(h));
    Bfh[(size_t)t * 8 + i] = h;
    Bfl[(size_t)t * 8 + i] = l;
  }
}

// ------------- fused layer2, q-pair batched: shared edge staging + dual-acc edge agg
//               (weights pinned to VGPRs, ILP-4) + two split-bf16 MFMA GEMM passes + mean -------------
__global__ __launch_bounds__(256, 5) void k_conv2(const float2* __restrict__ axp,
    const int* __restrict__ rowptrP, const int* __restrict__ colg,
    const float* __restrict__ invdegP, const int* __restrict__ perm,
    const float* __restrict__ wl1, const float* __restrict__ wr1, const float* __restrict__ b1,
    const unsigned short* __restrict__ Bfh, const unsigned short* __restrict__ Bfl,
    const float* __restrict__ b2,
    float* __restrict__ outs)
{
  // single LDS region: eb4 (edge stage, 20.7 KB) reused as At (16.6 KB) + ps after edge phase
  __shared__ __align__(16) char smem[(ECAP + ECAP / 16 + 4) * 16];
  float4*       eb4 = (float4*)smem;
  unsigned int* At  = (unsigned int*)smem;   // [k][slot] packed bf16 hi|lo, stride 65
  float*        ps  = (float*)smem;          // epilogue partials (aliases At, barrier-guarded)

  const int qp = blockIdx.y;                 // q-pair index: q0=2qp, q1=2qp+1
  const int q0 = 2 * qp, q1 = 2 * qp + 1;
  const int n0 = blockIdx.x * 64;
  const int tid = threadIdx.x;
  const int w = tid >> 6, lane = tid & 63;
  const float2* ax0 = axp + (size_t)q0 * NN;
  const float2* ax1 = axp + (size_t)q1 * NN;

  // per-lane CSR range (lane = permuted slot)
  const int slot = n0 + lane;
  const int r0 = rowptrP[min(slot, NN)];
  const int r1 = rowptrP[min(slot + 1, NN)];
  const int e0 = __builtin_amdgcn_readfirstlane(rowptrP[n0]);
  const int e1 = __builtin_amdgcn_readfirstlane(rowptrP[min(n0 + 64, NN)]);
  const int eblk = e1 - e0;
  const bool fits = eblk <= ECAP;            // block-uniform

  // stage edges once for BOTH q's: float4 = {(alpha,x)_q0, (alpha,x)_q1}
  if (fits) {
    for (int i = tid; i < eblk; i += 256) {
      int c = colg[e0 + i];
      float2 a0 = ax0[c], a1 = ax1[c];
      eb4[eb4idx(i)] = make_float4(a0.x, a0.y, a1.x, a1.y);
    }
  }
  __syncthreads();

  // wave w covers k-slice [16w, 16w+16); weights PINNED to VGPRs (avoid 2-SGPR-operand movs)
  f32x2 wl2[8], wr2[8], bb2[8];
  {
    const float4* wl4 = (const float4*)(wl1 + 16 * w);
    const float4* wr4 = (const float4*)(wr1 + 16 * w);
    const float4* b4  = (const float4*)(b1  + 16 * w);
    #pragma unroll
    for (int j = 0; j < 4; ++j) {
      float4 a = wl4[j], b = wr4[j], c = b4[j];
      wl2[2*j] = {a.x, a.y}; wl2[2*j+1] = {a.z, a.w};
      wr2[2*j] = {b.x, b.y}; wr2[2*j+1] = {b.z, b.w};
      bb2[2*j] = {c.x, c.y}; bb2[2*j+1] = {c.z, c.w};
    }
    #pragma unroll
    for (int j = 0; j < 8; ++j)
      asm("" : "+v"(wl2[j]), "+v"(wr2[j]), "+v"(bb2[j]));   // force VGPR residency
  }
  f32x2 acc2a[8], acc2b[8];
  #pragma unroll
  for (int j = 0; j < 8; ++j) { acc2a[j] = {0.f, 0.f}; acc2b[j] = {0.f, 0.f}; }
  const f32x2 zer2 = {0.f, 0.f};

  auto bodyA = [&](float a, float x) {
    f32x2 ca = {a, a}, cx = {x, x};
    #pragma unroll
    for (int j = 0; j < 8; ++j) {
      f32x2 z = __builtin_elementwise_fma(ca, wl2[j],
                __builtin_elementwise_fma(cx, wr2[j], bb2[j]));
      acc2a[j] += __builtin_elementwise_max(z, zer2);
    }
  };
  auto bodyB = [&](float a, float x) {
    f32x2 ca = {a, a}, cx = {x, x};
    #pragma unroll
    for (int j = 0; j < 8; ++j) {
      f32x2 z = __builtin_elementwise_fma(ca, wl2[j],
                __builtin_elementwise_fma(cx, wr2[j], bb2[j]));
      acc2b[j] += __builtin_elementwise_max(z, zer2);
    }
  };

  const int dg = r1 - r0;
  if (fits) {
    const int i0 = r0 - e0;
    int e = 0;
    for (; e + 3 < dg; e += 4) {                     // ILP-4: 4 float4 reads in flight
      float4 v0 = eb4[eb4idx(i0 + e)];
      float4 v1 = eb4[eb4idx(i0 + e + 1)];
      float4 v2 = eb4[eb4idx(i0 + e + 2)];
      float4 v3 = eb4[eb4idx(i0 + e + 3)];
      bodyA(v0.x, v0.y); bodyB(v0.z, v0.w);
      bodyA(v1.x, v1.y); bodyB(v1.z, v1.w);
      bodyA(v2.x, v2.y); bodyB(v2.z, v2.w);
      bodyA(v3.x, v3.y); bodyB(v3.z, v3.w);
    }
    for (; e < dg; ++e) {
      float4 v0 = eb4[eb4idx(i0 + e)];
      bodyA(v0.x, v0.y); bodyB(v0.z, v0.w);
    }
  } else {                                           // rare oversized block: L2 gather both q
    const int* __restrict__ cp = colg + r0;
    for (int e = 0; e < dg; ++e) {
      int c = cp[e];
      float2 a0 = ax0[c], a1 = ax1[c];
      bodyA(a0.x, a0.y); bodyB(a1.x, a1.y);
    }
  }
  __syncthreads();                                   // all eb4 reads done; region becomes At/ps

  const int nlo = lane & 15, lg = lane >> 4;
  const int gslot = n0 + w * 16 + nlo;
  const bool valid = gslot < NN;
  const int pnode = valid ? perm[gslot] : 0;
  const float iv = invdegP[min(slot, NN - 1)];

  #pragma unroll
  for (int qi = 0; qi < 2; ++qi) {
    const f32x2* acc2 = qi ? acc2b : acc2a;
    const float2* axq = qi ? ax1 : ax0;
    const int     qq  = qi ? q1 : q0;

    // finalize: *invdeg, split bf16 hi/lo, pack, store At[k][lane]
    {
      const f32x2 iv2 = {iv, iv};
      #pragma unroll
      for (int j = 0; j < 8; ++j) {
        f32x2 a = acc2[j] * iv2;
        unsigned int H = cvtpk(a.x, a.y);
        float f0 = __builtin_bit_cast(float, H << 16);
        float f1 = __builtin_bit_cast(float, H & 0xffff0000u);
        unsigned int L = cvtpk(a.x - f0, a.y - f1);
        At[(16 * w + 2 * j + 0) * 65 + lane] = __builtin_amdgcn_perm(H, L, 0x05040100u);
        At[(16 * w + 2 * j + 1) * 65 + lane] = __builtin_amdgcn_perm(H, L, 0x07060302u);
      }
    }
    __syncthreads();

    // split-bf16 MFMA GEMM: wave w rows w*16..w*16+15, cols 0..63
    float2 own = make_float2(0.f, 0.f);
    if (valid) own = axq[pnode];
    f32x4 acc[4] = {{0.f,0.f,0.f,0.f},{0.f,0.f,0.f,0.f},{0.f,0.f,0.f,0.f},{0.f,0.f,0.f,0.f}};

    #pragma unroll 1
    for (int ks = 0; ks < 2; ++ks) {                 // agg2 @ Wl2 (k 0..63)
      unsigned int u[8];
      #pragma unroll
      for (int i = 0; i < 8; ++i)
        u[i] = At[(ks * 32 + lg * 8 + i) * 65 + w * 16 + nlo];
      int4 ah, al;
      ah.x = __builtin_amdgcn_perm(u[1], u[0], 0x07060302u);
      ah.y = __builtin_amdgcn_perm(u[3], u[2], 0x07060302u);
      ah.z = __builtin_amdgcn_perm(u[5], u[4], 0x07060302u);
      ah.w = __builtin_amdgcn_perm(u[7], u[6], 0x07060302u);
      al.x = __builtin_amdgcn_perm(u[1], u[0], 0x05040100u);
      al.y = __builtin_amdgcn_perm(u[3], u[2], 0x05040100u);
      al.z = __builtin_amdgcn_perm(u[5], u[4], 0x05040100u);
      al.w = __builtin_amdgcn_perm(u[7], u[6], 0x05040100u);
      short8 ah8 = __builtin_bit_cast(short8, ah);
      short8 al8 = __builtin_bit_cast(short8, al);
      const short8* bh = (const short8*)(Bfh + (size_t)ks * 4 * 64 * 8);
      const short8* bl = (const short8*)(Bfl + (size_t)ks * 4 * 64 * 8);
      #pragma unroll
      for (int tn = 0; tn < 4; ++tn) {
        short8 bhv = bh[tn * 64 + lane];
        short8 blv = bl[tn * 64 + lane];
        acc[tn] = __builtin_amdgcn_mfma_f32_16x16x32_bf16(al8, bhv, acc[tn], 0, 0, 0);
        acc[tn] = __builtin_amdgcn_mfma_f32_16x16x32_bf16(ah8, blv, acc[tn], 0, 0, 0);
        acc[tn] = __builtin_amdgcn_mfma_f32_16x16x32_bf16(ah8, bhv, acc[tn], 0, 0, 0);
      }
    }

    #pragma unroll 1
    for (int ks = 2; ks < 4; ++ks) {                 // h1own @ Wr2 (k 64..127), in-reg
      const int kb = (ks - 2) * 32 + lg * 8;
      float4 wa0 = *(const float4*)(wl1 + kb), wa1 = *(const float4*)(wl1 + kb + 4);
      float4 wb0 = *(const float4*)(wr1 + kb), wb1 = *(const float4*)(wr1 + kb + 4);
      float4 bc0 = *(const float4*)(b1 + kb),  bc1 = *(const float4*)(b1 + kb + 4);
      float hv[8];
      hv[0] = fmaxf(fmaf(own.x, wa0.x, fmaf(own.y, wb0.x, bc0.x)), 0.f);
      hv[1] = fmaxf(fmaf(own.x, wa0.y, fmaf(own.y, wb0.y, bc0.y)), 0.f);
      hv[2] = fmaxf(fmaf(own.x, wa0.z, fmaf(own.y, wb0.z, bc0.z)), 0.f);
      hv[3] = fmaxf(fmaf(own.x, wa0.w, fmaf(own.y, wb0.w, bc0.w)), 0.f);
      hv[4] = fmaxf(fmaf(own.x, wa1.x, fmaf(own.y, wb1.x, bc1.x)), 0.f);
      hv[5] = fmaxf(fmaf(own.x, wa1.y, fmaf(own.y, wb1.y, bc1.y)), 0.f);
      hv[6] = fmaxf(fmaf(own.x, wa1.z, fmaf(own.y, wb1.z, bc1.z)), 0.f);
      hv[7] = fmaxf(fmaf(own.x, wa1.w, fmaf(own.y, wb1.w, bc1.w)), 0.f);
      int4 ah, al;
      #pragma unroll
      for (int p = 0; p < 4; ++p) {
        unsigned int H = cvtpk(hv[2*p], hv[2*p+1]);
        float f0 = __builtin_bit_cast(float, H << 16);
        float f1 = __builtin_bit_cast(float, H & 0xffff0000u);
        unsigned int L = cvtpk(hv[2*p] - f0, hv[2*p+1] - f1);
        ((unsigned int*)&ah)[p] = H;
        ((unsigned int*)&al)[p] = L;
      }
      short8 ah8 = __builtin_bit_cast(short8, ah);
      short8 al8 = __builtin_bit_cast(short8, al);
      const short8* bh = (const short8*)(Bfh + (size_t)ks * 4 * 64 * 8);
      const short8* bl = (const short8*)(Bfl + (size_t)ks * 4 * 64 * 8);
      #pragma unroll
      for (int tn = 0; tn < 4; ++tn) {
        short8 bhv = bh[tn * 64 + lane];
        short8 blv = bl[tn * 64 + lane];
        acc[tn] = __builtin_amdgcn_mfma_f32_16x16x32_bf16(al8, bhv, acc[tn], 0, 0, 0);
        acc[tn] = __builtin_amdgcn_mfma_f32_16x16x32_bf16(ah8, blv, acc[tn], 0, 0, 0);
        acc[tn] = __builtin_amdgcn_mfma_f32_16x16x32_bf16(ah8, bhv, acc[tn], 0, 0, 0);
      }
    }
    __syncthreads();                                 // At reads done before ps aliasing

    // epilogue: bias + relu + column sums (C: col=lane&15, row=4*lg+r)
    #pragma unroll
    for (int tn = 0; tn < 4; ++tn) {
      const float bias = b2[tn * 16 + nlo];
      float s = 0.f;
      #pragma unroll
      for (int r = 0; r < 4; ++r) {
        int nslot = n0 + w * 16 + lg * 4 + r;
        float v = fmaxf(acc[tn][r] + bias, 0.f);
        if (nslot < NN) s += v;
      }
      s += __shfl_xor(s, 16, 64);
      s += __shfl_xor(s, 32, 64);
      if (lg == 0) ps[w * 64 + tn * 16 + nlo] = s;
    }
    __syncthreads();
    if (tid < 64) {
      float t = ps[tid] + ps[64 + tid] + ps[128 + tid] + ps[192 + tid];
      int b = qq / TT, tt = qq % TT;
      atomicAdd(&outs[((size_t)tt * BB + b) * 64 + tid], t);
    }
    __syncthreads();                                 // ps reads done before next finalize
  }
}

// ------------- GRU side -------------
__global__ void k_T(const float* __restrict__ Wih, const float* __restrict__ Whh,
                    float* __restrict__ WihT, float* __restrict__ WhhT) {
  int id = blockIdx.x * 256 + threadIdx.x;
  if (id < 384 * 64)  { int r = id / 64;  int c = id % 64;  WihT[c * 384 + r] = Wih[id]; }
  if (id < 384 * 128) { int r = id / 128; int c = id % 128; WhhT[c * 384 + r] = Whh[id]; }
}

__global__ __launch_bounds__(384) void k_gi(const float* __restrict__ outs,
                                            const float* __restrict__ WihT,
                                            const float* __restrict__ bih,
                                            float* __restrict__ gi) {
  int g = blockIdx.x;                   // t*BB + b
  __shared__ float xl[64];
  int r = threadIdx.x;
  if (r < 64) xl[r] = outs[(size_t)g * 64 + r] * (1.0f / (float)NN);
  __syncthreads();
  float acc = bih[r];
  #pragma unroll 8
  for (int c = 0; c < 64; ++c) acc = fmaf(WihT[c * 384 + r], xl[c], acc);
  gi[(size_t)g * 384 + r] = acc;
}

__global__ __launch_bounds__(384) void k_gru(const float* __restrict__ gi,
                                             const float* __restrict__ WhhT,
                                             const float* __restrict__ bhh,
                                             const float* __restrict__ h1W,
                                             const float* __restrict__ h1b,
                                             const float* __restrict__ h2W,
                                             const float* __restrict__ h2b,
                                             float* __restrict__ out) {
  int b = blockIdx.x, r = threadIdx.x;
  __shared__ float hl[128];
  __shared__ float ghl[384];
  __shared__ float t1l[64];
  float wreg[128];
  #pragma unroll
  for (int c = 0; c < 128; ++c) wreg[c] = WhhT[c * 384 + r];   // coalesced
  float bh = bhh[r];
  if (r < 128) hl[r] = 0.f;
  __syncthreads();
  for (int t = 0; t < TT; ++t) {
    float acc = bh;
    #pragma unroll
    for (int c = 0; c < 128; ++c) acc = fmaf(wreg[c], hl[c], acc);
    ghl[r] = acc;
    __syncthreads();
    if (r < 128) {
      const float* gio = gi + ((size_t)t * BB + b) * 384;
      float ir = gio[r], iz = gio[128 + r], inn = gio[256 + r];
      float hr = ghl[r], hz = ghl[128 + r], hn = ghl[256 + r];
      float rg = 1.f / (1.f + expf(-(ir + hr)));
      float zg = 1.f / (1.f + expf(-(iz + hz)));
      float ng = tanhf(inn + rg * hn);
      hl[r] = (1.f - zg) * ng + zg * hl[r];
    }
    __syncthreads();
  }
  if (r < 64) {
    float a = h1b[r];
    #pragma unroll
    for (int c = 0; c < 128; ++c) a = fmaf(hl[c], h1W[c * 64 + r], a);
    t1l[r] = fmaxf(a, 0.f);
  }
  __syncthreads();
  if (r == 0) {
    float o = h2b[0];
    for (int j = 0; j < 64; ++j) o = fmaf(t1l[j], h2W[j], o);
    out[b] = o;
  }
}

extern "C" void kernel_launch(void* const* d_in, const int* in_sizes, int n_in,
                              void* d_out, int out_size, void* d_ws, size_t ws_size,
                              hipStream_t stream) {
  const float* xseq = (const float*)d_in[0];
  const int*   ei   = (const int*)d_in[1];
  const float* s1Wl = (const float*)d_in[2];
  const float* s1Wr = (const float*)d_in[3];
  const float* s1b  = (const float*)d_in[4];
  const float* s2Wl = (const float*)d_in[5];
  const float* s2Wr = (const float*)d_in[6];
  const float* s2b  = (const float*)d_in[7];
  const float* gWih = (const float*)d_in[8];
  const float* gWhh = (const float*)d_in[9];
  const float* gbih = (const float*)d_in[10];
  const float* gbhh = (const float*)d_in[11];
  const float* h1W  = (const float*)d_in[12];
  const float* h1b  = (const float*)d_in[13];
  const float* h2W  = (const float*)d_in[14];
  const float* h2b  = (const float*)d_in[15];
  float* out = (float*)d_out;

  char* ws = (char*)d_ws;
  int*    deg     = (int*)(ws + 0);              //   20480
  int*    fill    = (int*)(ws + 20480);          //   20480
  float*  outs    = (float*)(ws + 40960);        //  262144
  int*    rowptrP = (int*)(ws + 303104);         //   20480
  float*  invdegP = (float*)(ws + 323584);       //   20480
  int*    col     = (int*)(ws + 344064);         //  320512
  int*    perm    = (int*)(ws + 664576);         //   20480
  int*    rank    = (int*)(ws + 685056);         //   20480
  float2* axp     = (float2*)(ws + 705536);      // 40960000
  float*  WihT    = (float*)(ws + 41665536);     //   98304
  float*  WhhT    = (float*)(ws + 41763840);     //  196608
  float*  gi      = (float*)(ws + 41960448);     // 1572864
  unsigned short* Bfh = (unsigned short*)(ws + 43533312);  // 16384
  unsigned short* Bfl = (unsigned short*)(ws + 43549696);  // 16384 (end ~43.57 MB)

  const int* srcI = ei;
  const int* dstI = ei + EE;

  hipMemsetAsync(d_ws, 0, 303104, stream);       // deg + fill + outs
  k_deg  <<<(EE + 255) / 256, 256, 0, stream>>>(dstI, deg);
  k_sort <<<1, 1024, 0, stream>>>(deg, perm, rank);
  k_scan <<<1, 1024, 0, stream>>>(deg, perm, rowptrP, invdegP);
  k_fill <<<(EE + 255) / 256, 256, 0, stream>>>(srcI, dstI, rowptrP, rank, fill, col);
  k_wsplit<<<4, 256, 0, stream>>>(s2Wl, s2Wr, Bfh, Bfl);
  k_axp  <<<BB * TT, 256, 0, stream>>>(xseq, rowptrP, col, invdegP, perm, axp);
  dim3 g2(79, BB * TT / 2);
  k_conv2<<<g2, 256, 0, stream>>>(axp, rowptrP, col, invdegP, perm,
                                  s1Wl, s1Wr, s1b, Bfh, Bfl, s2b, outs);
  k_T    <<<192, 256, 0, stream>>>(gWih, gWhh, WihT, WhhT);
  k_gi   <<<BB * TT, 384, 0, stream>>>(outs, WihT, gbih, gi);
  k_gru  <<<BB, 384, 0, stream>>>(gi, WhhT, gbhh, h1W, h1b, h2W, h2b, out);
}

// Round 15
// 1117.597 us; speedup vs baseline: 1.5704x; 1.5704x over previous
//
#include <hip/hip_runtime.h>

#define NN 5000
#define EE 80000
#define BB 16
#define TT 64
// HG=64, HT=128

constexpr int ECAP = 1216;                // staged edges per block

typedef float  f32x2 __attribute__((ext_vector_type(2)));
typedef float  f32x4 __attribute__((ext_vector_type(4)));
typedef short  short8 __attribute__((ext_vector_type(8)));

__device__ inline unsigned short f2bf(float f) {           // RNE fp32->bf16 (setup kernels)
  unsigned int u = __builtin_bit_cast(unsigned int, f);
  u = (u + 0x7fffu + ((u >> 16) & 1u)) >> 16;
  return (unsigned short)u;
}
__device__ inline float bf2f(unsigned short h) {
  unsigned int u = ((unsigned int)h) << 16;
  return __builtin_bit_cast(float, u);
}
// v_cvt_pk_bf16_f32: dst = [bf16(hi) : bf16(lo)]  (lo in bits 0..15)
__device__ inline unsigned int cvtpk(float lo, float hi) {
  unsigned int r;
  asm("v_cvt_pk_bf16_f32 %0, %1, %2" : "=v"(r) : "v"(lo), "v"(hi));
  return r;
}
// float4-stride pad: idx delta per lane ≈ 17 ≡ 1 (mod 8) -> lanes walk all 8 bank-quads
__device__ inline int eb4idx(int t) { return t + (t >> 4); }

// ---------------- CSR build (degree-sorted node order) ----------------
__global__ void k_deg(const int* __restrict__ dst, int* __restrict__ deg) {
  int e = blockIdx.x * 256 + threadIdx.x;
  if (e < EE) atomicAdd(&deg[dst[e]], 1);
}

// counting sort of nodes by degree -> perm (slot->node), rank (node->slot)
__global__ __launch_bounds__(1024) void k_sort(const int* __restrict__ deg,
                                               int* __restrict__ perm,
                                               int* __restrict__ rank) {
  __shared__ int hist[256];
  int t = threadIdx.x;
  if (t < 256) hist[t] = 0;
  __syncthreads();
  for (int n = t; n < NN; n += 1024) atomicAdd(&hist[min(deg[n], 255)], 1);
  __syncthreads();
  if (t == 0) { int run = 0; for (int d = 0; d < 256; ++d) { int c = hist[d]; hist[d] = run; run += c; } }
  __syncthreads();
  for (int n = t; n < NN; n += 1024) {
    int d = min(deg[n], 255);
    int p = atomicAdd(&hist[d], 1);
    perm[p] = n;
    rank[n] = p;
  }
}

__global__ __launch_bounds__(1024) void k_scan(const int* __restrict__ deg,
                                               const int* __restrict__ perm,
                                               int* __restrict__ rowptrP,
                                               float* __restrict__ invdegP) {
  __shared__ int part[1024];
  int t = threadIdx.x;
  const int CH = 5;                      // 1024*5 >= 5000
  int base = t * CH;
  int cnt[CH];
  int s = 0;
  for (int i = 0; i < CH; ++i) {
    int idx = base + i;
    int d = (idx < NN) ? deg[perm[idx]] : 0;
    cnt[i] = d; s += d;
  }
  part[t] = s;
  __syncthreads();
  for (int off = 1; off < 1024; off <<= 1) {
    int v = (t >= off) ? part[t - off] : 0;
    __syncthreads();
    part[t] += v;
    __syncthreads();
  }
  int run = part[t] - s;                 // exclusive prefix
  for (int i = 0; i < CH; ++i) {
    int idx = base + i;
    if (idx < NN) {
      rowptrP[idx] = run;
      invdegP[idx] = 1.0f / fmaxf((float)cnt[i], 1.0f);
      run += cnt[i];
    }
  }
  if (t == 0) rowptrP[NN] = EE;
}

__global__ void k_fill(const int* __restrict__ src, const int* __restrict__ dst,
                       const int* __restrict__ rowptrP, const int* __restrict__ rank,
                       int* __restrict__ fill, int* __restrict__ col) {
  int e = blockIdx.x * 256 + threadIdx.x;
  if (e < EE) {
    int r = rank[dst[e]];
    int p = atomicAdd(&fill[r], 1);
    col[rowptrP[r] + p] = src[e];
  }
}

// ------------- per-(b,t) scalar aggregation: alpha = invdeg * sum x[src] -------------
__global__ __launch_bounds__(256) void k_axp(const float* __restrict__ xseq,
                                             const int* __restrict__ rowptrP,
                                             const int* __restrict__ colg,
                                             const float* __restrict__ invdegP,
                                             const int* __restrict__ perm,
                                             float2* __restrict__ axp) {
  int q = blockIdx.x;                    // q = b*TT + t
  __shared__ float xl[NN];
  const float* xs = xseq + (size_t)q * NN;
  for (int i = threadIdx.x; i < NN; i += 256) xl[i] = xs[i];
  __syncthreads();
  for (int ii = threadIdx.x; ii < NN; ii += 256) {   // permuted slots: sorted -> uniform trips
    int r0 = rowptrP[ii], r1 = rowptrP[ii + 1];
    float s = 0.f;
    for (int i = r0; i < r1; ++i) s += xl[colg[i]];
    int pn = perm[ii];
    axp[(size_t)q * NN + pn] = make_float2(s * invdegP[ii], xl[pn]);
  }
}

// ------------- pre-split W2 stack into bf16 hi/lo MFMA fragments -------------
__global__ void k_wsplit(const float* __restrict__ Wl2, const float* __restrict__ Wr2,
                         unsigned short* __restrict__ Bfh, unsigned short* __restrict__ Bfl) {
  int t = blockIdx.x * 256 + threadIdx.x;
  if (t >= 16 * 64) return;
  int frag = t >> 6, lane = t & 63;
  int ks = frag >> 2, tn = frag & 3;
  int nlo = lane & 15, lg = lane >> 4;
  #pragma unroll
  for (int i = 0; i < 8; ++i) {
    int k = ks * 32 + lg * 8 + i;
    int n = tn * 16 + nlo;
    float v = (k < 64) ? Wl2[k * 64 + n] : Wr2[(k - 64) * 64 + n];
    unsigned short h = f2bf(v);
    unsigned short l = f2bf(v - bf2f(h));
    Bfh[(size_t)t * 8 + i] = h;
    Bfl[(size_t)t * 8 + i] = l;
  }
}

// ------------- fused layer2, q-pair batched: shared edge staging + dual-acc edge agg
//               (weights laundered to VGPRs via shfl) + two split-bf16 MFMA GEMM passes + mean -------------
__global__ __launch_bounds__(256, 4) void k_conv2(const float2* __restrict__ axp,
    const int* __restrict__ rowptrP, const int* __restrict__ colg,
    const float* __restrict__ invdegP, const int* __restrict__ perm,
    const float* __restrict__ wl1, const float* __restrict__ wr1, const float* __restrict__ b1,
    const unsigned short* __restrict__ Bfh, const unsigned short* __restrict__ Bfl,
    const float* __restrict__ b2,
    float* __restrict__ outs)
{
  // single LDS region: eb4 (edge stage, 20.7 KB) reused as At (16.6 KB) + ps after edge phase
  __shared__ __align__(16) char smem[(ECAP + ECAP / 16 + 4) * 16];
  float4*       eb4 = (float4*)smem;
  unsigned int* At  = (unsigned int*)smem;   // [k][slot] packed bf16 hi|lo, stride 65
  float*        ps  = (float*)smem;          // epilogue partials (aliases At, barrier-guarded)

  const int qp = blockIdx.y;                 // q-pair index: q0=2qp, q1=2qp+1
  const int q0 = 2 * qp, q1 = 2 * qp + 1;
  const int n0 = blockIdx.x * 64;
  const int tid = threadIdx.x;
  const int w = tid >> 6, lane = tid & 63;
  const float2* ax0 = axp + (size_t)q0 * NN;
  const float2* ax1 = axp + (size_t)q1 * NN;

  // per-lane CSR range (lane = permuted slot)
  const int slot = n0 + lane;
  const int r0 = rowptrP[min(slot, NN)];
  const int r1 = rowptrP[min(slot + 1, NN)];
  const int e0 = __builtin_amdgcn_readfirstlane(rowptrP[n0]);
  const int e1 = __builtin_amdgcn_readfirstlane(rowptrP[min(n0 + 64, NN)]);
  const int eblk = e1 - e0;
  const bool fits = eblk <= ECAP;            // block-uniform

  // stage edges once for BOTH q's: float4 = {(alpha,x)_q0, (alpha,x)_q1}
  if (fits) {
    for (int i = tid; i < eblk; i += 256) {
      int c = colg[e0 + i];
      float2 a0 = ax0[c], a1 = ax1[c];
      eb4[eb4idx(i)] = make_float4(a0.x, a0.y, a1.x, a1.y);
    }
  }
  __syncthreads();

  // wave w covers k-slice [16w, 16w+16); weights laundered through lane-0 shfl:
  // values are wave-uniform (unchanged), but the compiler cannot prove it ->
  // they live in VGPRs, so the inner FMAs never need 2 SGPR operands (no v_mov tax).
  f32x2 wl2[8], wr2[8], bb2[8];
  {
    const float4* wl4 = (const float4*)(wl1 + 16 * w);
    const float4* wr4 = (const float4*)(wr1 + 16 * w);
    const float4* b4  = (const float4*)(b1  + 16 * w);
    #pragma unroll
    for (int j = 0; j < 4; ++j) {
      float4 a = wl4[j], b = wr4[j], c = b4[j];
      a.x = __shfl(a.x, 0); a.y = __shfl(a.y, 0); a.z = __shfl(a.z, 0); a.w = __shfl(a.w, 0);
      b.x = __shfl(b.x, 0); b.y = __shfl(b.y, 0); b.z = __shfl(b.z, 0); b.w = __shfl(b.w, 0);
      c.x = __shfl(c.x, 0); c.y = __shfl(c.y, 0); c.z = __shfl(c.z, 0); c.w = __shfl(c.w, 0);
      wl2[2*j] = {a.x, a.y}; wl2[2*j+1] = {a.z, a.w};
      wr2[2*j] = {b.x, b.y}; wr2[2*j+1] = {b.z, b.w};
      bb2[2*j] = {c.x, c.y}; bb2[2*j+1] = {c.z, c.w};
    }
  }
  f32x2 acc2a[8], acc2b[8];
  #pragma unroll
  for (int j = 0; j < 8; ++j) { acc2a[j] = {0.f, 0.f}; acc2b[j] = {0.f, 0.f}; }
  const f32x2 zer2 = {0.f, 0.f};

  auto bodyA = [&](float a, float x) {
    f32x2 ca = {a, a}, cx = {x, x};
    #pragma unroll
    for (int j = 0; j < 8; ++j) {
      f32x2 z = __builtin_elementwise_fma(ca, wl2[j],
                __builtin_elementwise_fma(cx, wr2[j], bb2[j]));
      acc2a[j] += __builtin_elementwise_max(z, zer2);
    }
  };
  auto bodyB = [&](float a, float x) {
    f32x2 ca = {a, a}, cx = {x, x};
    #pragma unroll
    for (int j = 0; j < 8; ++j) {
      f32x2 z = __builtin_elementwise_fma(ca, wl2[j],
                __builtin_elementwise_fma(cx, wr2[j], bb2[j]));
      acc2b[j] += __builtin_elementwise_max(z, zer2);
    }
  };

  const int dg = r1 - r0;
  if (fits) {
    const int i0 = r0 - e0;
    int e = 0;
    for (; e + 1 < dg; e += 2) {                     // 2 float4 reads in flight
      float4 v0 = eb4[eb4idx(i0 + e)];
      float4 v1 = eb4[eb4idx(i0 + e + 1)];
      bodyA(v0.x, v0.y); bodyB(v0.z, v0.w);
      bodyA(v1.x, v1.y); bodyB(v1.z, v1.w);
    }
    if (e < dg) {
      float4 v0 = eb4[eb4idx(i0 + e)];
      bodyA(v0.x, v0.y); bodyB(v0.z, v0.w);
    }
  } else {                                           // rare oversized block: L2 gather both q
    const int* __restrict__ cp = colg + r0;
    for (int e = 0; e < dg; ++e) {
      int c = cp[e];
      float2 a0 = ax0[c], a1 = ax1[c];
      bodyA(a0.x, a0.y); bodyB(a1.x, a1.y);
    }
  }
  __syncthreads();                                   // all eb4 reads done; region becomes At/ps

  const int nlo = lane & 15, lg = lane >> 4;
  const int gslot = n0 + w * 16 + nlo;
  const bool valid = gslot < NN;
  const int pnode = valid ? perm[gslot] : 0;
  const float iv = invdegP[min(slot, NN - 1)];

  #pragma unroll
  for (int qi = 0; qi < 2; ++qi) {
    const f32x2* acc2 = qi ? acc2b : acc2a;
    const float2* axq = qi ? ax1 : ax0;
    const int     qq  = qi ? q1 : q0;

    // finalize: *invdeg, split bf16 hi/lo, pack, store At[k][lane]
    {
      const f32x2 iv2 = {iv, iv};
      #pragma unroll
      for (int j = 0; j < 8; ++j) {
        f32x2 a = acc2[j] * iv2;
        unsigned int H = cvtpk(a.x, a.y);
        float f0 = __builtin_bit_cast(float, H << 16);
        float f1 = __builtin_bit_cast(float, H & 0xffff0000u);
        unsigned int L = cvtpk(a.x - f0, a.y - f1);
        At[(16 * w + 2 * j + 0) * 65 + lane] = __builtin_amdgcn_perm(H, L, 0x05040100u);
        At[(16 * w + 2 * j + 1) * 65 + lane] = __builtin_amdgcn_perm(H, L, 0x07060302u);
      }
    }
    __syncthreads();

    // split-bf16 MFMA GEMM: wave w rows w*16..w*16+15, cols 0..63
    float2 own = make_float2(0.f, 0.f);
    if (valid) own = axq[pnode];
    f32x4 acc[4] = {{0.f,0.f,0.f,0.f},{0.f,0.f,0.f,0.f},{0.f,0.f,0.f,0.f},{0.f,0.f,0.f,0.f}};

    #pragma unroll 1
    for (int ks = 0; ks < 2; ++ks) {                 // agg2 @ Wl2 (k 0..63)
      unsigned int u[8];
      #pragma unroll
      for (int i = 0; i < 8; ++i)
        u[i] = At[(ks * 32 + lg * 8 + i) * 65 + w * 16 + nlo];
      int4 ah, al;
      ah.x = __builtin_amdgcn_perm(u[1], u[0], 0x07060302u);
      ah.y = __builtin_amdgcn_perm(u[3], u[2], 0x07060302u);
      ah.z = __builtin_amdgcn_perm(u[5], u[4], 0x07060302u);
      ah.w = __builtin_amdgcn_perm(u[7], u[6], 0x07060302u);
      al.x = __builtin_amdgcn_perm(u[1], u[0], 0x05040100u);
      al.y = __builtin_amdgcn_perm(u[3], u[2], 0x05040100u);
      al.z = __builtin_amdgcn_perm(u[5], u[4], 0x05040100u);
      al.w = __builtin_amdgcn_perm(u[7], u[6], 0x05040100u);
      short8 ah8 = __builtin_bit_cast(short8, ah);
      short8 al8 = __builtin_bit_cast(short8, al);
      const short8* bh = (const short8*)(Bfh + (size_t)ks * 4 * 64 * 8);
      const short8* bl = (const short8*)(Bfl + (size_t)ks * 4 * 64 * 8);
      #pragma unroll
      for (int tn = 0; tn < 4; ++tn) {
        short8 bhv = bh[tn * 64 + lane];
        short8 blv = bl[tn * 64 + lane];
        acc[tn] = __builtin_amdgcn_mfma_f32_16x16x32_bf16(al8, bhv, acc[tn], 0, 0, 0);
        acc[tn] = __builtin_amdgcn_mfma_f32_16x16x32_bf16(ah8, blv, acc[tn], 0, 0, 0);
        acc[tn] = __builtin_amdgcn_mfma_f32_16x16x32_bf16(ah8, bhv, acc[tn], 0, 0, 0);
      }
    }

    #pragma unroll 1
    for (int ks = 2; ks < 4; ++ks) {                 // h1own @ Wr2 (k 64..127), in-reg
      const int kb = (ks - 2) * 32 + lg * 8;
      float4 wa0 = *(const float4*)(wl1 + kb), wa1 = *(const float4*)(wl1 + kb + 4);
      float4 wb0 = *(const float4*)(wr1 + kb), wb1 = *(const float4*)(wr1 + kb + 4);
      float4 bc0 = *(const float4*)(b1 + kb),  bc1 = *(const float4*)(b1 + kb + 4);
      float hv[8];
      hv[0] = fmaxf(fmaf(own.x, wa0.x, fmaf(own.y, wb0.x, bc0.x)), 0.f);
      hv[1] = fmaxf(fmaf(own.x, wa0.y, fmaf(own.y, wb0.y, bc0.y)), 0.f);
      hv[2] = fmaxf(fmaf(own.x, wa0.z, fmaf(own.y, wb0.z, bc0.z)), 0.f);
      hv[3] = fmaxf(fmaf(own.x, wa0.w, fmaf(own.y, wb0.w, bc0.w)), 0.f);
      hv[4] = fmaxf(fmaf(own.x, wa1.x, fmaf(own.y, wb1.x, bc1.x)), 0.f);
      hv[5] = fmaxf(fmaf(own.x, wa1.y, fmaf(own.y, wb1.y, bc1.y)), 0.f);
      hv[6] = fmaxf(fmaf(own.x, wa1.z, fmaf(own.y, wb1.z, bc1.z)), 0.f);
      hv[7] = fmaxf(fmaf(own.x, wa1.w, fmaf(own.y, wb1.w, bc1.w)), 0.f);
      int4 ah, al;
      #pragma unroll
      for (int p = 0; p < 4; ++p) {
        unsigned int H = cvtpk(hv[2*p], hv[2*p+1]);
        float f0 = __builtin_bit_cast(float, H << 16);
        float f1 = __builtin_bit_cast(float, H & 0xffff0000u);
        unsigned int L = cvtpk(hv[2*p] - f0, hv[2*p+1] - f1);
        ((unsigned int*)&ah)[p] = H;
        ((unsigned int*)&al)[p] = L;
      }
      short8 ah8 = __builtin_bit_cast(short8, ah);
      short8 al8 = __builtin_bit_cast(short8, al);
      const short8* bh = (const short8*)(Bfh + (size_t)ks * 4 * 64 * 8);
      const short8* bl = (const short8*)(Bfl + (size_t)ks * 4 * 64 * 8);
      #pragma unroll
      for (int tn = 0; tn < 4; ++tn) {
        short8 bhv = bh[tn * 64 + lane];
        short8 blv = bl[tn * 64 + lane];
        acc[tn] = __builtin_amdgcn_mfma_f32_16x16x32_bf16(al8, bhv, acc[tn], 0, 0, 0);
        acc[tn] = __builtin_amdgcn_mfma_f32_16x16x32_bf16(ah8, blv, acc[tn], 0, 0, 0);
        acc[tn] = __builtin_amdgcn_mfma_f32_16x16x32_bf16(ah8, bhv, acc[tn], 0, 0, 0);
      }
    }
    __syncthreads();                                 // At reads done before ps aliasing

    // epilogue: bias + relu + column sums (C: col=lane&15, row=4*lg+r)
    #pragma unroll
    for (int tn = 0; tn < 4; ++tn) {
      const float bias = b2[tn * 16 + nlo];
      float s = 0.f;
      #pragma unroll
      for (int r = 0; r < 4; ++r) {
        int nslot = n0 + w * 16 + lg * 4 + r;
        float v = fmaxf(acc[tn][r] + bias, 0.f);
        if (nslot < NN) s += v;
      }
      s += __shfl_xor(s, 16, 64);
      s += __shfl_xor(s, 32, 64);
      if (lg == 0) ps[w * 64 + tn * 16 + nlo] = s;
    }
    __syncthreads();
    if (tid < 64) {
      float t = ps[tid] + ps[64 + tid] + ps[128 + tid] + ps[192 + tid];
      int b = qq / TT, tt = qq % TT;
      atomicAdd(&outs[((size_t)tt * BB + b) * 64 + tid], t);
    }
    __syncthreads();                                 // ps reads done before next finalize
  }
}

// ------------- GRU side -------------
__global__ void k_T(const float* __restrict__ Wih, const float* __restrict__ Whh,
                    float* __restrict__ WihT, float* __restrict__ WhhT) {
  int id = blockIdx.x * 256 + threadIdx.x;
  if (id < 384 * 64)  { int r = id / 64;  int c = id % 64;  WihT[c * 384 + r] = Wih[id]; }
  if (id < 384 * 128) { int r = id / 128; int c = id % 128; WhhT[c * 384 + r] = Whh[id]; }
}

__global__ __launch_bounds__(384) void k_gi(const float* __restrict__ outs,
                                            const float* __restrict__ WihT,
                                            const float* __restrict__ bih,
                                            float* __restrict__ gi) {
  int g = blockIdx.x;                   // t*BB + b
  __shared__ float xl[64];
  int r = threadIdx.x;
  if (r < 64) xl[r] = outs[(size_t)g * 64 + r] * (1.0f / (float)NN);
  __syncthreads();
  float acc = bih[r];
  #pragma unroll 8
  for (int c = 0; c < 64; ++c) acc = fmaf(WihT[c * 384 + r], xl[c], acc);
  gi[(size_t)g * 384 + r] = acc;
}

__global__ __launch_bounds__(384) void k_gru(const float* __restrict__ gi,
                                             const float* __restrict__ WhhT,
                                             const float* __restrict__ bhh,
                                             const float* __restrict__ h1W,
                                             const float* __restrict__ h1b,
                                             const float* __restrict__ h2W,
                                             const float* __restrict__ h2b,
                                             float* __restrict__ out) {
  int b = blockIdx.x, r = threadIdx.x;
  __shared__ float hl[128];
  __shared__ float ghl[384];
  __shared__ float t1l[64];
  float wreg[128];
  #pragma unroll
  for (int c = 0; c < 128; ++c) wreg[c] = WhhT[c * 384 + r];   // coalesced
  float bh = bhh[r];
  if (r < 128) hl[r] = 0.f;
  __syncthreads();
  for (int t = 0; t < TT; ++t) {
    float acc = bh;
    #pragma unroll
    for (int c = 0; c < 128; ++c) acc = fmaf(wreg[c], hl[c], acc);
    ghl[r] = acc;
    __syncthreads();
    if (r < 128) {
      const float* gio = gi + ((size_t)t * BB + b) * 384;
      float ir = gio[r], iz = gio[128 + r], inn = gio[256 + r];
      float hr = ghl[r], hz = ghl[128 + r], hn = ghl[256 + r];
      float rg = 1.f / (1.f + expf(-(ir + hr)));
      float zg = 1.f / (1.f + expf(-(iz + hz)));
      float ng = tanhf(inn + rg * hn);
      hl[r] = (1.f - zg) * ng + zg * hl[r];
    }
    __syncthreads();
  }
  if (r < 64) {
    float a = h1b[r];
    #pragma unroll
    for (int c = 0; c < 128; ++c) a = fmaf(hl[c], h1W[c * 64 + r], a);
    t1l[r] = fmaxf(a, 0.f);
  }
  __syncthreads();
  if (r == 0) {
    float o = h2b[0];
    for (int j = 0; j < 64; ++j) o = fmaf(t1l[j], h2W[j], o);
    out[b] = o;
  }
}

extern "C" void kernel_launch(void* const* d_in, const int* in_sizes, int n_in,
                              void* d_out, int out_size, void* d_ws, size_t ws_size,
                              hipStream_t stream) {
  const float* xseq = (const float*)d_in[0];
  const int*   ei   = (const int*)d_in[1];
  const float* s1Wl = (const float*)d_in[2];
  const float* s1Wr = (const float*)d_in[3];
  const float* s1b  = (const float*)d_in[4];
  const float* s2Wl = (const float*)d_in[5];
  const float* s2Wr = (const float*)d_in[6];
  const float* s2b  = (const float*)d_in[7];
  const float* gWih = (const float*)d_in[8];
  const float* gWhh = (const float*)d_in[9];
  const float* gbih = (const float*)d_in[10];
  const float* gbhh = (const float*)d_in[11];
  const float* h1W  = (const float*)d_in[12];
  const float* h1b  = (const float*)d_in[13];
  const float* h2W  = (const float*)d_in[14];
  const float* h2b  = (const float*)d_in[15];
  float* out = (float*)d_out;

  char* ws = (char*)d_ws;
  int*    deg     = (int*)(ws + 0);              //   20480
  int*    fill    = (int*)(ws + 20480);          //   20480
  float*  outs    = (float*)(ws + 40960);        //  262144
  int*    rowptrP = (int*)(ws + 303104);         //   20480
  float*  invdegP = (float*)(ws + 323584);       //   20480
  int*    col     = (int*)(ws + 344064);         //  320512
  int*    perm    = (int*)(ws + 664576);         //   20480
  int*    rank    = (int*)(ws + 685056);         //   20480
  float2* axp     = (float2*)(ws + 705536);      // 40960000
  float*  WihT    = (float*)(ws + 41665536);     //   98304
  float*  WhhT    = (float*)(ws + 41763840);     //  196608
  float*  gi      = (float*)(ws + 41960448);     // 1572864
  unsigned short* Bfh = (unsigned short*)(ws + 43533312);  // 16384
  unsigned short* Bfl = (unsigned short*)(ws + 43549696);  // 16384 (end ~43.57 MB)

  const int* srcI = ei;
  const int* dstI = ei + EE;

  hipMemsetAsync(d_ws, 0, 303104, stream);       // deg + fill + outs
  k_deg  <<<(EE + 255) / 256, 256, 0, stream>>>(dstI, deg);
  k_sort <<<1, 1024, 0, stream>>>(deg, perm, rank);
  k_scan <<<1, 1024, 0, stream>>>(deg, perm, rowptrP, invdegP);
  k_fill <<<(EE + 255) / 256, 256, 0, stream>>>(srcI, dstI, rowptrP, rank, fill, col);
  k_wsplit<<<4, 256, 0, stream>>>(s2Wl, s2Wr, Bfh, Bfl);
  k_axp  <<<BB * TT, 256, 0, stream>>>(xseq, rowptrP, col, invdegP, perm, axp);
  dim3 g2(79, BB * TT / 2);
  k_conv2<<<g2, 256, 0, stream>>>(axp, rowptrP, col, invdegP, perm,
                                  s1Wl, s1Wr, s1b, Bfh, Bfl, s2b, outs);
  k_T    <<<192, 256, 0, stream>>>(gWih, gWhh, WihT, WhhT);
  k_gi   <<<BB * TT, 384, 0, stream>>>(outs, WihT, gbih, gi);
  k_gru  <<<BB, 384, 0, stream>>>(gi, WhhT, gbhh, h1W, h1b, h2W, h2b, out);
}